// Round 4
// baseline (479.003 us; speedup 1.0000x reference)
//
#include <hip/hip_runtime.h>
#include <hip/hip_bf16.h>

typedef unsigned int u32;

#define BN 32
#define CC 192
#define HH 64
#define WW 64
#define HWSZ (HH*WW)            // 4096
#define OHH 32
#define OWW 32
#define NVALID_SCALE 131072.0f  // BN*HH*WW per channel
#define PLW 65                  // plane row: [33 even cols | 32 odd cols] (de-interleaved)
#define PLSZ (PLW*PLW)          // 4225 words per plane
#define NPLANE (12*BN)          // 2 br * 6 words * 32 n = 384 planes
// column c (=iw+1, 0..64) -> de-interleaved index: even c -> c/2 (0..32), odd c -> 33+c/2 (33..64)

// ---------------- K1: per-(c,n) partial sum / sumsq ----------------
__global__ __launch_bounds__(256) void k_stats(const float* __restrict__ x,
                                               float* __restrict__ partial) {
    int b = blockIdx.x;            // b = c*32 + n
    int c = b >> 5, n = b & 31;
    const float4* p = (const float4*)(x + ((size_t)(n * CC + c) << 12));
    int tid = threadIdx.x;
    float s = 0.f, s2 = 0.f;
#pragma unroll
    for (int k = 0; k < 4; ++k) {
        float4 f = p[tid + 256 * k];
        s  += f.x + f.y + f.z + f.w;
        s2 += f.x * f.x + f.y * f.y + f.z * f.z + f.w * f.w;
    }
#pragma unroll
    for (int off = 32; off > 0; off >>= 1) {
        s  += __shfl_down(s, off, 64);
        s2 += __shfl_down(s2, off, 64);
    }
    __shared__ float red[8];
    int wv = tid >> 6, ln = tid & 63;
    if (ln == 0) { red[wv * 2] = s; red[wv * 2 + 1] = s2; }
    __syncthreads();
    if (tid == 0) {
        partial[b * 2]     = red[0] + red[2] + red[4] + red[6];
        partial[b * 2 + 1] = red[1] + red[3] + red[5] + red[7];
    }
}

// ---------------- K2: finalize BN coefs (both branches), 1 block/channel ----------------
__global__ __launch_bounds__(64) void k_coef(const float* __restrict__ partial,
        const float* __restrict__ g1, const float* __restrict__ b1,
        const float* __restrict__ g2, const float* __restrict__ b2,
        float* __restrict__ coef) {
    int c = blockIdx.x;
    int t = threadIdx.x;
    int half = t >> 5, i = t & 31;
    float v = partial[(c * 32 + i) * 2 + half];
#pragma unroll
    for (int off = 16; off > 0; off >>= 1) v += __shfl_down(v, off, 32);
    float S2 = __shfl(v, 32, 64);   // lane 32 holds sumsq reduction
    if (t == 0) {
        float S = v;
        const float inv = 1.0f / NVALID_SCALE;
        float mu  = S * inv;
        float var = S2 * inv - mu * mu;
        float r   = 1.0f / sqrtf(var + 1e-5f);
        float s1 = g1[c] * r, t1 = b1[c] - mu * s1;
        float s2 = g2[c] * r, t2 = b2[c] - mu * s2;
        ((float4*)coef)[c] = make_float4(s1, t1, s2, t2);
    }
}

// ---------------- K3: sign-pack weights (k-major, j-minor) + edge popcount sums ----------------
// wp2 layout: [((br*16+g)*54 + k)*12 + j]  where oc = g*12+j, k = (kh*3+kw)*6+w6
// wsum layout: [(br*192+oc)*4] = {Wrow0, Wcol0, Wcorner, 0}
__global__ __launch_bounds__(256) void k_pack_w(const float* __restrict__ w1,
        const float* __restrict__ w2, u32* __restrict__ wp2, u32* __restrict__ wsum) {
    __shared__ float wl[CC * 9];
    __shared__ u32 ww[54];
    int b  = blockIdx.x;
    int br = b / CC, oc = b - br * CC;
    int g  = oc / 12, j = oc - g * 12;
    const float* W = (br ? w2 : w1) + (size_t)oc * CC * 9;
    int tid = threadIdx.x;
    for (int i = tid; i < CC * 9; i += 256) wl[i] = W[i];
    __syncthreads();
    if (tid < 54) {
        int w6 = tid % 6, pos = tid / 6;
        u32 word = 0;
#pragma unroll
        for (int bb = 0; bb < 32; ++bb) {
            if (wl[(w6 * 32 + bb) * 9 + pos] > 0.f) word |= (1u << bb);
        }
        wp2[((size_t)(br * 16 + g) * 54 + tid) * 12 + j] = word;
        ww[tid] = word;
    }
    __syncthreads();
    if (tid == 0) {
        int Wt[9];
#pragma unroll
        for (int t = 0; t < 9; ++t) {
            int s = 0;
#pragma unroll
            for (int w6 = 0; w6 < 6; ++w6) s += __popc(ww[t * 6 + w6]);
            Wt[t] = s;
        }
        wsum[b * 4 + 0] = (u32)(Wt[0] + Wt[1] + Wt[2]);  // top row kh=0
        wsum[b * 4 + 1] = (u32)(Wt[0] + Wt[3] + Wt[6]);  // left col kw=0
        wsum[b * 4 + 2] = (u32)Wt[0];                    // corner
        wsum[b * 4 + 3] = 0;
    }
}

// ---------------- K4: zero act halo (row ih=-1 and col iw=-1 of each plane) ----------------
// de-interleaved: col c=0 maps to index 0 of each row -> same positions as before
__global__ __launch_bounds__(192) void k_halo(u32* __restrict__ act) {
    u32* pl = act + (size_t)blockIdx.x * PLSZ;
    int t = threadIdx.x;
    if (t < PLW) pl[t] = 0;                       // row ih=-1 (all 65 words)
    else if (t < 2 * PLW - 1) pl[(t - PLW + 1) * PLW] = 0;  // col idx 0 (rows 1..64)
}

// ---------------- K5: binarize + bit-pack activations, word-planar + de-interleaved cols ----------------
// act plane p = (br*6 + g)*32 + n; word at row (ih+1), col-index deint(iw+1)
__global__ __launch_bounds__(256) void k_pack_act(const float* __restrict__ x,
        const float* __restrict__ coef, u32* __restrict__ act) {
    int bx = blockIdx.x;            // 0..127: n*4 + quarter
    int g  = blockIdx.y;            // word group 0..5
    int n = bx >> 2;
    int px0 = (bx & 3) * 1024 + threadIdx.x * 4;   // 4 px per thread, w0 = px0&63 in {0,4,..,60}
    int h = px0 >> 6, w0 = px0 & 63;
    const float*  xb = x + (size_t)n * CC * HWSZ + px0;
    const float4* c4 = (const float4*)coef;
    u32 p1[4] = {0,0,0,0}, p2[4] = {0,0,0,0};
#pragma unroll 8
    for (int bb = 0; bb < 32; ++bb) {
        int ch = g * 32 + bb;
        float4 v = *(const float4*)(xb + (size_t)ch * HWSZ);
        float4 cf = c4[ch];
        u32 bit = 1u << bb;
        if (v.x * cf.x + cf.y > 0.f) p1[0] |= bit;
        if (v.y * cf.x + cf.y > 0.f) p1[1] |= bit;
        if (v.z * cf.x + cf.y > 0.f) p1[2] |= bit;
        if (v.w * cf.x + cf.y > 0.f) p1[3] |= bit;
        if (v.x * cf.z + cf.w > 0.f) p2[0] |= bit;
        if (v.y * cf.z + cf.w > 0.f) p2[1] |= bit;
        if (v.z * cf.z + cf.w > 0.f) p2[2] |= bit;
        if (v.w * cf.z + cf.w > 0.f) p2[3] |= bit;
    }
    // cols c = w0+1 (odd), w0+2 (even), w0+3 (odd), w0+4 (even)
    // odd idx: 33+w0/2, 33+w0/2+1 ; even idx: w0/2+1, w0/2+2
    size_t rb1 = ((size_t)(0 * 6 + g) * BN + n) * PLSZ + (size_t)(h + 1) * PLW;
    size_t rb2 = ((size_t)(1 * 6 + g) * BN + n) * PLSZ + (size_t)(h + 1) * PLW;
    int ei = w0 / 2 + 1, oi = 33 + w0 / 2;
    *(uint2*)(act + rb1 + ei) = make_uint2(p1[1], p1[3]);
    *(uint2*)(act + rb1 + oi) = make_uint2(p1[0], p1[2]);
    *(uint2*)(act + rb2 + ei) = make_uint2(p2[1], p2[3]);
    *(uint2*)(act + rb2 + oi) = make_uint2(p2[0], p2[2]);
}

// ---------------- K6: XNOR conv + bias + relu + avgpool shortcut ----------------
// grid 2048 = 512 px-tiles * 4 ocg-quads; block = 4 waves; wave = 64 px (2 oh x 32 ow),
// wave handles 12 oc (both branches). Act tile in LDS; k-outer/j-inner popcount so each
// act word is ds_read ONCE; weights [k][12j] wave-uniform -> SGPR runs.
__global__ __launch_bounds__(256, 4) void k_conv(
        const u32* __restrict__ act, const u32* __restrict__ wp2,
        const u32* __restrict__ wsum, const float* __restrict__ x,
        const float* __restrict__ bias1, const float* __restrict__ bias2,
        float* __restrict__ out) {
    __shared__ u32 s_act[12 * 5 * PLW];   // 15600 B
    int b    = blockIdx.x;
    int tile = b >> 2;                  // (n, ohp)
    int n    = tile >> 4, ohp = tile & 15;
    int tid  = threadIdx.x;
    // ---- stage act rows [4*ohp .. 4*ohp+4] of all 12 planes (straight copy) ----
    {
        int rowbase = 4 * ohp;
        for (int i = tid; i < 12 * 5 * PLW; i += 256) {
            int q   = i / (5 * PLW);
            int rem = i - q * (5 * PLW);
            s_act[i] = act[((size_t)q * BN + n) * PLSZ + (size_t)rowbase * PLW + rem];
        }
    }
    __syncthreads();
    int wid  = __builtin_amdgcn_readfirstlane((int)(tid >> 6));
    int g    = (b & 3) * 4 + wid;            // oc-group 0..15
    int ocbase = g * 12;
    int lane = tid & 63;
    int ow = lane & 31, lh = lane >> 5;
    int oh = 2 * ohp + lh;
    int topE  = (oh == 0), leftE = (ow == 0);
    int nv192 = CC * ((topE ? 2 : 3) * (leftE ? 2 : 3));
    float sc[12];
#pragma unroll 1
    for (int br = 0; br < 2; ++br) {
        // base: row 2*lh, col-deint base ow (kw=0 -> +0, kw=1 -> +33, kw=2 -> +1)
        const u32* ap  = &s_act[br * (6 * 5 * PLW) + (2 * lh) * PLW + ow];
        const u32* wq2 = wp2 + (size_t)(br * 16 + g) * 648;
        int acc[12];
#pragma unroll
        for (int j = 0; j < 12; ++j) acc[j] = 0;
#pragma unroll
        for (int t = 0; t < 9; ++t) {
            int kh = t / 3, kw = t % 3;
            int coff = (kw == 0) ? 0 : (kw == 1 ? 33 : 1);
#pragma unroll
            for (int w6 = 0; w6 < 6; ++w6) {
                u32 av = ap[w6 * (5 * PLW) + kh * PLW + coff];
                const u32* wr = wq2 + (t * 6 + w6) * 12;
#pragma unroll
                for (int j = 0; j < 12; ++j) acc[j] += __popc(av ^ wr[j]);
            }
        }
        const u32*   wsb = wsum + (size_t)(br * CC + ocbase) * 4;
        const float* bsp = (br ? bias2 : bias1) + ocbase;
#pragma unroll
        for (int j = 0; j < 12; ++j) {
            int Wr = (int)wsb[j * 4], Wc = (int)wsb[j * 4 + 1], Wk = (int)wsb[j * 4 + 2];
            int corr = (topE ? Wr : 0) + (leftE ? Wc : 0) - ((topE & leftE) ? Wk : 0);
            int dot = nv192 - 2 * acc[j] + 2 * corr;
            int oc = ocbase + j;
            float y = (float)dot + bsp[j];
            if (br == 0) {
                const float* xp = x + (((size_t)n * CC + oc) * HH + 2 * oh) * WW + 2 * ow;
                float2 r0 = *(const float2*)xp;
                float2 r1 = *(const float2*)(xp + WW);
                sc[j] = (r0.x + r0.y + r1.x + r1.y) * 0.25f;
            }
            out[((size_t)(n * 384 + br * CC + oc) * OHH + oh) * OWW + ow] =
                fmaxf(y, 0.f) + sc[j];
        }
    }
}

extern "C" void kernel_launch(void* const* d_in, const int* in_sizes, int n_in,
                              void* d_out, int out_size, void* d_ws, size_t ws_size,
                              hipStream_t stream) {
    const float* x     = (const float*)d_in[0];
    const float* g1    = (const float*)d_in[1];
    const float* b1    = (const float*)d_in[2];
    const float* w1    = (const float*)d_in[3];
    const float* bias1 = (const float*)d_in[4];
    const float* g2    = (const float*)d_in[5];
    const float* b2    = (const float*)d_in[6];
    const float* w2    = (const float*)d_in[7];
    const float* bias2 = (const float*)d_in[8];
    float* out = (float*)d_out;
    char* ws = (char*)d_ws;
    // ws layout (all regions fully written before read; halo zeroed by k_halo):
    float* partial = (float*)(ws);             // 12288 f   -> 49152 B
    float* coef    = (float*)(ws + 49152);     // 768 f     -> 3072 B
    u32*   wp2     = (u32*)  (ws + 52224);     // 20736 u32 -> 82944 B
    u32*   wsum    = (u32*)  (ws + 135168);    // 1536 u32  -> 6144 B
    u32*   act     = (u32*)  (ws + 141312);    // 384*4225 u32 -> 6489600 B

    hipLaunchKernelGGL(k_stats,    dim3(CC * BN),      dim3(256), 0, stream, x, partial);
    hipLaunchKernelGGL(k_coef,     dim3(CC),           dim3(64),  0, stream, partial, g1, b1, g2, b2, coef);
    hipLaunchKernelGGL(k_pack_w,   dim3(2 * CC),       dim3(256), 0, stream, w1, w2, wp2, wsum);
    hipLaunchKernelGGL(k_halo,     dim3(NPLANE),       dim3(192), 0, stream, act);
    hipLaunchKernelGGL(k_pack_act, dim3(128, 6),       dim3(256), 0, stream, x, coef, act);
    hipLaunchKernelGGL(k_conv,     dim3(BN * 16 * 4),  dim3(256), 0, stream, act, wp2, wsum, x, bias1, bias2, out);
}

// Round 5
// 246.958 us; speedup vs baseline: 1.9396x; 1.9396x over previous
//
#include <hip/hip_runtime.h>
#include <hip/hip_bf16.h>

typedef unsigned int u32;

#define BN 32
#define CC 192
#define HH 64
#define WW 64
#define HWSZ (HH*WW)            // 4096
#define OHH 32
#define OWW 32
#define NVALID_SCALE 131072.0f  // BN*HH*WW per channel
#define PLW 65                  // plane row: [33 even cols | 32 odd cols] (de-interleaved)
#define PLSZ (PLW*PLW)          // 4225 words per plane
#define NPLANE (12*BN)          // 2 br * 6 words * 32 n = 384 planes
// column c (=iw+1, 0..64) -> de-interleaved index: even c -> c/2 (0..32), odd c -> 33+c/2 (33..64)

// ---------------- K1: per-(c,n) partial sum / sumsq ----------------
__global__ __launch_bounds__(256) void k_stats(const float* __restrict__ x,
                                               float* __restrict__ partial) {
    int b = blockIdx.x;            // b = c*32 + n
    int c = b >> 5, n = b & 31;
    const float4* p = (const float4*)(x + ((size_t)(n * CC + c) << 12));
    int tid = threadIdx.x;
    float s = 0.f, s2 = 0.f;
#pragma unroll
    for (int k = 0; k < 4; ++k) {
        float4 f = p[tid + 256 * k];
        s  += f.x + f.y + f.z + f.w;
        s2 += f.x * f.x + f.y * f.y + f.z * f.z + f.w * f.w;
    }
#pragma unroll
    for (int off = 32; off > 0; off >>= 1) {
        s  += __shfl_down(s, off, 64);
        s2 += __shfl_down(s2, off, 64);
    }
    __shared__ float red[8];
    int wv = tid >> 6, ln = tid & 63;
    if (ln == 0) { red[wv * 2] = s; red[wv * 2 + 1] = s2; }
    __syncthreads();
    if (tid == 0) {
        partial[b * 2]     = red[0] + red[2] + red[4] + red[6];
        partial[b * 2 + 1] = red[1] + red[3] + red[5] + red[7];
    }
}

// ---------------- K2: finalize BN coefs (both branches), 1 block/channel ----------------
__global__ __launch_bounds__(64) void k_coef(const float* __restrict__ partial,
        const float* __restrict__ g1, const float* __restrict__ b1,
        const float* __restrict__ g2, const float* __restrict__ b2,
        float* __restrict__ coef) {
    int c = blockIdx.x;
    int t = threadIdx.x;
    int half = t >> 5, i = t & 31;
    float v = partial[(c * 32 + i) * 2 + half];
#pragma unroll
    for (int off = 16; off > 0; off >>= 1) v += __shfl_down(v, off, 32);
    float S2 = __shfl(v, 32, 64);   // lane 32 holds sumsq reduction
    if (t == 0) {
        float S = v;
        const float inv = 1.0f / NVALID_SCALE;
        float mu  = S * inv;
        float var = S2 * inv - mu * mu;
        float r   = 1.0f / sqrtf(var + 1e-5f);
        float s1 = g1[c] * r, t1 = b1[c] - mu * s1;
        float s2 = g2[c] * r, t2 = b2[c] - mu * s2;
        ((float4*)coef)[c] = make_float4(s1, t1, s2, t2);
    }
}

// ---------------- K3: sign-pack weights (oc-major, 54 contiguous) + edge popcounts ----------------
// wp layout: [(br*192+oc)*54 + (kh*3+kw)*6 + w6], bit b = ic (w6*32+b)
// wsum layout: [(br*192+oc)*4] = {Wrow0, Wcol0, Wcorner, 0}
__global__ __launch_bounds__(256) void k_pack_w(const float* __restrict__ w1,
        const float* __restrict__ w2, u32* __restrict__ wp, u32* __restrict__ wsum) {
    __shared__ float wl[CC * 9];
    __shared__ u32 ww[54];
    int b  = blockIdx.x;
    int br = b / CC, oc = b - br * CC;
    const float* W = (br ? w2 : w1) + (size_t)oc * CC * 9;
    int tid = threadIdx.x;
    for (int i = tid; i < CC * 9; i += 256) wl[i] = W[i];
    __syncthreads();
    if (tid < 54) {
        int w6 = tid % 6, pos = tid / 6;
        u32 word = 0;
#pragma unroll
        for (int bb = 0; bb < 32; ++bb) {
            if (wl[(w6 * 32 + bb) * 9 + pos] > 0.f) word |= (1u << bb);
        }
        wp[(size_t)b * 54 + tid] = word;
        ww[tid] = word;
    }
    __syncthreads();
    if (tid == 0) {
        int Wt[9];
#pragma unroll
        for (int t = 0; t < 9; ++t) {
            int s = 0;
#pragma unroll
            for (int w6 = 0; w6 < 6; ++w6) s += __popc(ww[t * 6 + w6]);
            Wt[t] = s;
        }
        wsum[b * 4 + 0] = (u32)(Wt[0] + Wt[1] + Wt[2]);  // top row kh=0
        wsum[b * 4 + 1] = (u32)(Wt[0] + Wt[3] + Wt[6]);  // left col kw=0
        wsum[b * 4 + 2] = (u32)Wt[0];                    // corner
        wsum[b * 4 + 3] = 0;
    }
}

// ---------------- K4: zero act halo (row ih=-1 and col iw=-1 of each plane) ----------------
__global__ __launch_bounds__(192) void k_halo(u32* __restrict__ act) {
    u32* pl = act + (size_t)blockIdx.x * PLSZ;
    int t = threadIdx.x;
    if (t < PLW) pl[t] = 0;                       // row ih=-1 (all 65 words)
    else if (t < 2 * PLW - 1) pl[(t - PLW + 1) * PLW] = 0;  // col idx 0 (rows 1..64)
}

// ---------------- K5: binarize + bit-pack activations, word-planar + de-interleaved cols ----------------
// act plane p = (br*6 + g)*32 + n; word at row (ih+1), col-index deint(iw+1)
__global__ __launch_bounds__(256) void k_pack_act(const float* __restrict__ x,
        const float* __restrict__ coef, u32* __restrict__ act) {
    int bx = blockIdx.x;            // 0..127: n*4 + quarter
    int g  = blockIdx.y;            // word group 0..5
    int n = bx >> 2;
    int px0 = (bx & 3) * 1024 + threadIdx.x * 4;   // 4 px per thread, w0 = px0&63 in {0,4,..,60}
    int h = px0 >> 6, w0 = px0 & 63;
    const float*  xb = x + (size_t)n * CC * HWSZ + px0;
    const float4* c4 = (const float4*)coef;
    u32 p1[4] = {0,0,0,0}, p2[4] = {0,0,0,0};
#pragma unroll 8
    for (int bb = 0; bb < 32; ++bb) {
        int ch = g * 32 + bb;
        float4 v = *(const float4*)(xb + (size_t)ch * HWSZ);
        float4 cf = c4[ch];
        u32 bit = 1u << bb;
        if (v.x * cf.x + cf.y > 0.f) p1[0] |= bit;
        if (v.y * cf.x + cf.y > 0.f) p1[1] |= bit;
        if (v.z * cf.x + cf.y > 0.f) p1[2] |= bit;
        if (v.w * cf.x + cf.y > 0.f) p1[3] |= bit;
        if (v.x * cf.z + cf.w > 0.f) p2[0] |= bit;
        if (v.y * cf.z + cf.w > 0.f) p2[1] |= bit;
        if (v.z * cf.z + cf.w > 0.f) p2[2] |= bit;
        if (v.w * cf.z + cf.w > 0.f) p2[3] |= bit;
    }
    // cols c = w0+1 (odd), w0+2 (even), w0+3 (odd), w0+4 (even)
    size_t rb1 = ((size_t)(0 * 6 + g) * BN + n) * PLSZ + (size_t)(h + 1) * PLW;
    size_t rb2 = ((size_t)(1 * 6 + g) * BN + n) * PLSZ + (size_t)(h + 1) * PLW;
    int ei = w0 / 2 + 1, oi = 33 + w0 / 2;
    act[rb1 + ei]     = p1[1];
    act[rb1 + ei + 1] = p1[3];
    act[rb1 + oi]     = p1[0];
    act[rb1 + oi + 1] = p1[2];
    act[rb2 + ei]     = p2[1];
    act[rb2 + ei + 1] = p2[3];
    act[rb2 + oi]     = p2[0];
    act[rb2 + oi + 1] = p2[2];
}

// ---------------- K6: XNOR conv + bias + relu + avgpool shortcut ----------------
// grid 2048 = 512 px-tiles * 4 ocg-quads; block = 4 waves; wave = 64 px (2 oh x 32 ow),
// wave handles 12 oc (both branches). NO LDS: act loaded straight to VGPRs (a[54],
// coalesced stride-1 u32 loads from the de-interleaved planes, L2-hot, vmcnt domain);
// weights j-outer 54-word s_load streams (lgkmcnt domain). (256,3) -> 170 VGPR budget,
// a[54]+sc[12]+misc fits with no spill.
__global__ __launch_bounds__(256, 3) void k_conv(
        const u32* __restrict__ act, const u32* __restrict__ wp,
        const u32* __restrict__ wsum, const float* __restrict__ x,
        const float* __restrict__ bias1, const float* __restrict__ bias2,
        float* __restrict__ out) {
    int b    = blockIdx.x;
    int tile = b >> 2;                  // (n, ohp)
    int n    = tile >> 4, ohp = tile & 15;
    int tid  = threadIdx.x;
    int wid  = __builtin_amdgcn_readfirstlane((int)(tid >> 6));
    int g    = (b & 3) * 4 + wid;            // oc-group 0..15
    int ocbase = g * 12;
    int lane = tid & 63;
    int ow = lane & 31, lh = lane >> 5;
    int oh = 2 * ohp + lh;
    int topE  = (oh == 0), leftE = (ow == 0);
    int nv192 = CC * ((topE ? 2 : 3) * (leftE ? 2 : 3));
    int rowb  = 4 * ohp + 2 * lh;            // plane row for kh=0 (= 2*oh)
    float sc[12];
#pragma unroll 1
    for (int br = 0; br < 2; ++br) {
        // act fragments straight to VGPRs: a[(kh*3+kw)*6 + w6]
        u32 a[54];
#pragma unroll
        for (int w6 = 0; w6 < 6; ++w6) {
            const u32* pb = act + ((size_t)(br * 6 + w6) * BN + n) * PLSZ;
#pragma unroll
            for (int kh = 0; kh < 3; ++kh) {
                const u32* pr = pb + (size_t)(rowb + kh) * PLW;
                a[(kh * 3 + 0) * 6 + w6] = pr[ow];        // c=2ow   (even idx ow)
                a[(kh * 3 + 1) * 6 + w6] = pr[33 + ow];   // c=2ow+1 (odd  idx 33+ow)
                a[(kh * 3 + 2) * 6 + w6] = pr[ow + 1];    // c=2ow+2 (even idx ow+1)
            }
        }
        const u32*   wqb = wp   + (size_t)(br * CC + ocbase) * 54;
        const u32*   wsb = wsum + (size_t)(br * CC + ocbase) * 4;
        const float* bsp = (br ? bias2 : bias1) + ocbase;
#pragma unroll 2
        for (int j = 0; j < 12; ++j) {
            u32 wv[54];
#pragma unroll
            for (int k = 0; k < 54; ++k) wv[k] = wqb[j * 54 + k];
            int p = 0;
#pragma unroll
            for (int k = 0; k < 54; ++k) p += __popc(a[k] ^ wv[k]);
            int Wr = (int)wsb[j * 4], Wc = (int)wsb[j * 4 + 1], Wk = (int)wsb[j * 4 + 2];
            int corr = (topE ? Wr : 0) + (leftE ? Wc : 0) - ((topE & leftE) ? Wk : 0);
            int dot = nv192 - 2 * p + 2 * corr;
            int oc = ocbase + j;
            float y = (float)dot + bsp[j];
            if (br == 0) {
                const float* xp = x + (((size_t)n * CC + oc) * HH + 2 * oh) * WW + 2 * ow;
                float2 r0 = *(const float2*)xp;
                float2 r1 = *(const float2*)(xp + WW);
                sc[j] = (r0.x + r0.y + r1.x + r1.y) * 0.25f;
            }
            out[((size_t)(n * 384 + br * CC + oc) * OHH + oh) * OWW + ow] =
                fmaxf(y, 0.f) + sc[j];
        }
    }
}

extern "C" void kernel_launch(void* const* d_in, const int* in_sizes, int n_in,
                              void* d_out, int out_size, void* d_ws, size_t ws_size,
                              hipStream_t stream) {
    const float* x     = (const float*)d_in[0];
    const float* g1    = (const float*)d_in[1];
    const float* b1    = (const float*)d_in[2];
    const float* w1    = (const float*)d_in[3];
    const float* bias1 = (const float*)d_in[4];
    const float* g2    = (const float*)d_in[5];
    const float* b2    = (const float*)d_in[6];
    const float* w2    = (const float*)d_in[7];
    const float* bias2 = (const float*)d_in[8];
    float* out = (float*)d_out;
    char* ws = (char*)d_ws;
    // ws layout (all regions fully written before read; halo zeroed by k_halo):
    float* partial = (float*)(ws);             // 12288 f   -> 49152 B
    float* coef    = (float*)(ws + 49152);     // 768 f     -> 3072 B
    u32*   wp      = (u32*)  (ws + 52224);     // 20736 u32 -> 82944 B
    u32*   wsum    = (u32*)  (ws + 135168);    // 1536 u32  -> 6144 B
    u32*   act     = (u32*)  (ws + 141312);    // 384*4225 u32 -> 6489600 B

    hipLaunchKernelGGL(k_stats,    dim3(CC * BN),      dim3(256), 0, stream, x, partial);
    hipLaunchKernelGGL(k_coef,     dim3(CC),           dim3(64),  0, stream, partial, g1, b1, g2, b2, coef);
    hipLaunchKernelGGL(k_pack_w,   dim3(2 * CC),       dim3(256), 0, stream, w1, w2, wp, wsum);
    hipLaunchKernelGGL(k_halo,     dim3(NPLANE),       dim3(192), 0, stream, act);
    hipLaunchKernelGGL(k_pack_act, dim3(128, 6),       dim3(256), 0, stream, x, coef, act);
    hipLaunchKernelGGL(k_conv,     dim3(BN * 16 * 4),  dim3(256), 0, stream, act, wp, wsum, x, bias1, bias2, out);
}